// Round 11
// baseline (933.592 us; speedup 1.0000x reference)
//
#include <hip/hip_runtime.h>
#include <math.h>

#define BB 256
#define TT 512
#define KK 128

// smem layout (float indices)
#define SW_TT    0                    // [128][130] transposed trans = 16640
#define SW_AA    16640                // alpha double buffer [2][128] = 256
#define SW_TAGS  (16640 + 256)        // tagsf[512]
#define SW_TOTAL (16640 + 256 + 512)  // 17408 floats = 69.6 KB -> 2 blocks/CU

typedef float v2f __attribute__((ext_vector_type(2)));

// in-wave LDS ordering: no barrier, just drain lgkm (single-wave block)
#define WAVE_LGKM() asm volatile("s_waitcnt lgkmcnt(0)" ::: "memory")

// ============================================================================
// crf_wave: ONE WAVE per chain (grid 2*BB x 64). Lane l owns cols 2l,2l+1;
// T column-pair in 128 v2f REGISTERS; alpha in wave-private LDS (broadcast
// reads, same-wave writes) -> ZERO barriers in the 511-step recursion.
// Blocks [0,BB): viterbi (streams m_t, then runs the verified equality-match
// chase on the same wave). Blocks [BB,2BB): forward log-norm.
// ============================================================================
__global__ __launch_bounds__(64, 1) void crf_wave(
    const float* __restrict__ logits,     // [B,T,K]
    const int* __restrict__ labels,       // [B,T]
    const int* __restrict__ seq_lens,     // [B]
    const float* __restrict__ trans,      // [K,K]
    float* __restrict__ pred_out,         // [B,T] as float (d_out+1)
    float* __restrict__ negll,            // [B] in ws
    float* __restrict__ mOut)             // [B][T][K] in ws (t>=1 valid)
{
  __shared__ __align__(16) float smem[SW_TOTAL];
  float* tT    = smem + SW_TT;
  float* aA    = smem + SW_AA;
  float* tagsf = smem + SW_TAGS;

  const int l = threadIdx.x;            // 0..63
  const int j0 = 2 * l;                 // this lane's two columns
  const bool isV = blockIdx.x < BB;
  const int b = isV ? blockIdx.x : (blockIdx.x - BB);
  const int L = seq_lens[b];
  const float* lg = logits + (size_t)b * TT * KK;

  if (isV) {
    // ======================= VITERBI (1 wave, no barriers) =================
    // transposed trans for the chase (2-way bank stride -> free)
    for (int e = l; e < KK * KK; e += 64) {
      int i = e >> 7, j = e & 127;
      tT[j * 130 + i] = trans[e];
    }
    // T rows for this lane's two columns: tv[i] = T[i][j0..j0+1]
    v2f tv[128];
#pragma unroll
    for (int i = 0; i < 128; ++i)
      tv[i] = *(const v2f*)&trans[i * KK + j0];

    v2f afin = *(const v2f*)&lg[j0];    // alpha_0 for own cols
    *(v2f*)&aA[0 * 128 + j0] = afin;    // buffer 0 = alpha_0

    v2f emC[4], emN[4];
#pragma unroll
    for (int s = 0; s < 4; ++s) {
      int t2 = 1 + s; if (t2 > L - 1) t2 = (L > 1) ? (L - 1) : 0;
      emC[s] = *(const v2f*)&lg[t2 * KK + j0];
    }
    WAVE_LGKM();                        // alpha_0 + tT visible (same wave)

    for (int tc = 1; tc < L; tc += 4) {
#pragma unroll
      for (int s = 0; s < 4; ++s) {
        int t2 = tc + 4 + s; if (t2 > L - 1) t2 = L - 1;
        emN[s] = *(const v2f*)&lg[t2 * KK + j0];
      }
#pragma unroll
      for (int s = 0; s < 4; ++s) {
        const int t = tc + s;
        if (t >= L) break;
        // full 128-row max-plus for own 2 cols; broadcast LDS reads
        const float4* ap = (const float4*)&aA[((t & 1) ^ 1) * 128];
        float4 a0 = ap[0];
        v2f c0 = (v2f){a0.x, a0.x} + tv[0];   // exact IEEE adds
        v2f c1 = (v2f){a0.y, a0.y} + tv[1];
        v2f c2 = (v2f){a0.z, a0.z} + tv[2];
        v2f c3 = (v2f){a0.w, a0.w} + tv[3];
#pragma unroll
        for (int q = 1; q < 32; ++q) {
          float4 a4 = ap[q];
          c0 = __builtin_elementwise_max(c0, (v2f){a4.x, a4.x} + tv[4 * q + 0]);
          c1 = __builtin_elementwise_max(c1, (v2f){a4.y, a4.y} + tv[4 * q + 1]);
          c2 = __builtin_elementwise_max(c2, (v2f){a4.z, a4.z} + tv[4 * q + 2]);
          c3 = __builtin_elementwise_max(c3, (v2f){a4.w, a4.w} + tv[4 * q + 3]);
        }
        v2f m = __builtin_elementwise_max(
            __builtin_elementwise_max(c0, c1),
            __builtin_elementwise_max(c2, c3));          // full max (exact)
        v2f nav = m + emC[s];
        afin = nav;
        *(v2f*)&aA[(t & 1) * 128 + j0] = nav;            // same-wave publish
        *(v2f*)&mOut[(size_t)(b * TT + t) * KK + j0] = m;  // stream m_t
        WAVE_LGKM();                                     // write -> next read
      }
#pragma unroll
      for (int s = 0; s < 4; ++s) emC[s] = emN[s];
    }

    // final argmax across K (first-index ties) from register afin
    int last;
    {
      float v; int idx;
      if (afin.x >= afin.y) { v = afin.x; idx = j0; }
      else                  { v = afin.y; idx = j0 + 1; }
#pragma unroll
      for (int mm = 1; mm < 64; mm <<= 1) {
        float ov = __shfl_xor(v, mm);
        int oi = __shfl_xor(idx, mm);
        if (ov > v || (ov == v && oi < idx)) { v = ov; idx = oi; }
      }
      last = idx;                        // uniform across the wave
    }
    for (int t2 = l; t2 < TT; t2 += 64) tagsf[t2] = (float)last;
    // drain mOut stores (same wave) + tagsf before the chase
    asm volatile("s_waitcnt vmcnt(0) lgkmcnt(0)" ::: "memory");

    // ============ equality-match chase (R7/R9-verified, verbatim) ==========
    if (L >= 2) {
      const float* mb = mOut + (size_t)(b * TT) * KK + j0;
      const float* gb = lg + j0;
      int tag = last;
      v2f mvC = *(const v2f*)&mb[(size_t)(L - 1) * KK];   // m at current t

      v2f lg0, lg1, lg2, lg3, lg4, lg5, lg6, lg7;
      v2f mv0, mv1, mv2, mv3, mv4, mv5, mv6, mv7;
#define INITLD(PP) { int s_ = L - 2 - (PP); int sc_ = s_ < 0 ? 0 : s_;         \
      lg##PP = *(const v2f*)&gb[(size_t)sc_ * KK];                             \
      mv##PP = *(const v2f*)&mb[(size_t)sc_ * KK]; }
      INITLD(0) INITLD(1) INITLD(2) INITLD(3)
      INITLD(4) INITLD(5) INITLD(6) INITLD(7)
#undef INITLD

      int t = L - 1;

#define STEP_BODY(LG, MV, GUARDED)                                             \
      {                                                                        \
        const int tp = t - 1;                                                  \
        v2f aP;                                                                \
        if (GUARDED) aP = (tp >= 1) ? (MV + LG) : LG;                          \
        else         aP = MV + LG;                                             \
        int lanem = tag >> 1;                                                  \
        int txi = __builtin_amdgcn_readlane(__float_as_int(mvC.x), lanem);     \
        int tyi = __builtin_amdgcn_readlane(__float_as_int(mvC.y), lanem);     \
        float target = __int_as_float((tag & 1) ? tyi : txi);                  \
        v2f col = *(const v2f*)&tT[tag * 130 + j0];                            \
        v2f sv = aP + col;                 /* bit-exact phase-1 adds */        \
        bool h0 = (sv.x == target), h1 = (sv.y == target);                     \
        unsigned long long mask = __ballot(h0 || h1);                          \
        int first = __ffsll(mask) - 1;     /* lowest matching lane */          \
        int cand = h0 ? j0 : (j0 + 1);                                         \
        tag = __builtin_amdgcn_readlane(cand, first);                          \
        if (l == 0) tagsf[tp] = (float)tag;                                    \
        mvC = MV;                                                              \
      }

      while (t >= 9) {
#define MAIN_PHASE(PP)                                                         \
        STEP_BODY(lg##PP, mv##PP, false)                                       \
        { int sN = t - 9; int sc_ = sN < 0 ? 0 : sN;                           \
          lg##PP = *(const v2f*)&gb[(size_t)sc_ * KK];                         \
          mv##PP = *(const v2f*)&mb[(size_t)sc_ * KK]; }                       \
        --t;
        MAIN_PHASE(0) MAIN_PHASE(1) MAIN_PHASE(2) MAIN_PHASE(3)
        MAIN_PHASE(4) MAIN_PHASE(5) MAIN_PHASE(6) MAIN_PHASE(7)
#undef MAIN_PHASE
      }
      while (t >= 1) {
        const int tp = t - 1;
        int sc_ = tp < 1 ? 0 : tp;
        v2f lgE = *(const v2f*)&gb[(size_t)tp * KK];
        v2f mvE = *(const v2f*)&mb[(size_t)sc_ * KK];
        STEP_BODY(lgE, mvE, true)
        --t;
      }
#undef STEP_BODY
    }
    WAVE_LGKM();
#pragma unroll
    for (int k = 0; k < 8; ++k)
      pred_out[b * TT + l * 8 + k] = tagsf[l * 8 + k];

  } else {
    // ======================= FORWARD (1 wave, no barriers) =================
    v2f tw[128];
#pragma unroll
    for (int i = 0; i < 128; ++i) {
      v2f tr = *(const v2f*)&trans[i * KK + j0];
      tw[i].x = __expf(tr.x);
      tw[i].y = __expf(tr.y);
    }
    v2f efin;
    efin.x = __expf(lg[j0]);
    efin.y = __expf(lg[j0 + 1]);
    *(v2f*)&aA[0 * 128 + j0] = efin;
    float wm = 1.0f;                     // full-128 max of last chunk step

    v2f emC[4], emN[4];
#pragma unroll
    for (int s = 0; s < 4; ++s) {
      int t2 = 1 + s; if (t2 > L - 1) t2 = (L > 1) ? (L - 1) : 0;
      emC[s] = *(const v2f*)&lg[t2 * KK + j0];
    }
    WAVE_LGKM();

    float Cln = 0.0f;
    for (int tc = 1; tc < L; tc += 4) {
#pragma unroll
      for (int s = 0; s < 4; ++s) {
        int t2 = tc + 4 + s; if (t2 > L - 1) t2 = L - 1;
        emN[s] = *(const v2f*)&lg[t2 * KK + j0];
      }
      // renorm factor (exact pow2), once per 4-step chunk — wm wave-uniform
      float r;
      {
        int ex = (__float_as_int(wm) >> 23) & 255;
        r = __int_as_float((254 - ex) << 23);
        Cln += (float)(ex - 127) * 0.6931471805599453f;
      }
#pragma unroll
      for (int s = 0; s < 4; ++s) {
        const int t = tc + s;
        if (t >= L) break;
        const float4* ep = (const float4*)&aA[((t & 1) ^ 1) * 128];
        float4 a0 = ep[0];
        v2f c0 = (v2f){a0.x, a0.x} * tw[0];
        v2f c1 = (v2f){a0.y, a0.y} * tw[1];
        v2f c2 = (v2f){a0.z, a0.z} * tw[2];
        v2f c3 = (v2f){a0.w, a0.w} * tw[3];
#pragma unroll
        for (int q = 1; q < 32; ++q) {
          float4 a4 = ep[q];
          c0 += (v2f){a4.x, a4.x} * tw[4 * q + 0];   // pk_fma
          c1 += (v2f){a4.y, a4.y} * tw[4 * q + 1];
          c2 += (v2f){a4.z, a4.z} * tw[4 * q + 2];
          c3 += (v2f){a4.w, a4.w} * tw[4 * q + 3];
        }
        v2f S = (c0 + c1) + (c2 + c3);
        v2f em2 = emC[s];
        float evn0 = S.x * __expf(em2.x);
        float evn1 = S.y * __expf(em2.y);
        if (s == 0) { evn0 *= r; evn1 *= r; }
        efin = (v2f){evn0, evn1};
        *(v2f*)&aA[(t & 1) * 128 + j0] = efin;
        if (s == 3) {
          float t0 = fmaxf(evn0, evn1);
#pragma unroll
          for (int mm = 1; mm < 64; mm <<= 1) t0 = fmaxf(t0, __shfl_xor(t0, mm));
          wm = t0;
        }
        WAVE_LGKM();
      }
#pragma unroll
      for (int s = 0; s < 4; ++s) emC[s] = emN[s];
    }

    // final sum across K
    float es;
    {
      float ssum = efin.x + efin.y;
#pragma unroll
      for (int mm = 1; mm < 64; mm <<= 1) ssum += __shfl_xor(ssum, mm);
      es = ssum;
    }
    // gold-path score (64-lane strided)
    float sc = 0.0f;
    for (int tt2 = l; tt2 < L; tt2 += 64) {
      int lab = labels[b * TT + tt2];
      sc += lg[tt2 * KK + lab];
      if (tt2 >= 1) sc += trans[labels[b * TT + tt2 - 1] * KK + lab];
    }
#pragma unroll
    for (int mm = 1; mm < 64; mm <<= 1) sc += __shfl_xor(sc, mm);
    if (l == 0) negll[b] = (Cln + logf(es)) - sc;
  }
}

// ============================================================================
// FALLBACK: verbatim 438us two-block kernel (bp in ws), used if ws too small.
// ============================================================================
#define AIDX(i) ((i) + (((i) >> 5) << 2))
typedef unsigned short u16v2 __attribute__((ext_vector_type(2)));
template<int CTRL>
__device__ __forceinline__ int dpp_i(int x) {
  return __builtin_amdgcn_update_dpp(x, x, CTRL, 0xF, 0xF, true);
}
template<int CTRL>
__device__ __forceinline__ float dpp_f(float x) {
  return __int_as_float(dpp_i<CTRL>(__float_as_int(x)));
}
__device__ __forceinline__ float swz16_f(float x) {
  return __int_as_float(__builtin_amdgcn_ds_swizzle(__float_as_int(x), 0x401F));
}
__device__ __forceinline__ int pkminu16(int a, int b) {
  u16v2 av = *(u16v2*)&a, bv = *(u16v2*)&b;
  u16v2 r = __builtin_elementwise_min(av, bv);
  return *(int*)&r;
}
#define BARRIER_LGKM() asm volatile("s_waitcnt lgkmcnt(0)\ns_barrier" ::: "memory")

__global__ __launch_bounds__(512, 4) void crf_main_fb(
    const float* __restrict__ logits,
    const int* __restrict__ labels,
    const int* __restrict__ seq_lens,
    const float* __restrict__ trans,
    float* __restrict__ pred_out,
    float* __restrict__ negll,
    unsigned char* __restrict__ bp)
{
  const int tid = threadIdx.x;
  const int cg = tid >> 3, rg = tid & 7;
  const int j0 = cg * 2, i0 = rg * 16;

  if (blockIdx.x < BB) {
    const int b = blockIdx.x;
    const int L = seq_lens[b];
    __shared__ __align__(16) float av[2][144];
    __shared__ unsigned char tags[TT];
    __shared__ float rv[8]; __shared__ int ri[8];
    __shared__ int last_s;

    v2f tv[16];
#pragma unroll
    for (int ii = 0; ii < 16; ++ii)
      tv[ii] = *(const v2f*)&trans[(i0 + ii) * KK + j0];

    if (tid < KK) av[0][AIDX(tid)] = logits[(b * TT) * KK + tid];

    v2f emC[4], emN[4];
#pragma unroll
    for (int s = 0; s < 4; ++s) {
      int t2 = 1 + s; if (t2 > L - 1) t2 = (L > 1) ? (L - 1) : 0;
      emC[s] = *(const v2f*)&logits[(b * TT + t2) * KK + j0];
    }
    __syncthreads();

    unsigned int pw0 = 0, pw1 = 0; int pend_c = -1;

    for (int tc = 1; tc < L; tc += 4) {
#pragma unroll
      for (int s = 0; s < 4; ++s) {
        int t2 = tc + 4 + s; if (t2 > L - 1) t2 = L - 1;
        emN[s] = *(const v2f*)&logits[(b * TT + t2) * KK + j0];
      }
      if (pend_c >= 0 && rg == 1) {
        *(uint2*)(bp + (((b << 7) + pend_c) << 9) + (cg << 3)) =
            make_uint2(pw0, pw1);
      }
      unsigned int w0 = 0, w1 = 0;
#pragma unroll
      for (int s = 0; s < 4; ++s) {
        const int t = tc + s;
        if (t >= L) break;
        const float4* avr = (const float4*)(av[(t & 1) ^ 1] + AIDX(i0));
        v2f sv[16];
#pragma unroll
        for (int q = 0; q < 4; ++q) {
          float4 a4 = avr[q];
#pragma unroll
          for (int c = 0; c < 4; ++c) {
            float a = (c == 0) ? a4.x : (c == 1) ? a4.y : (c == 2) ? a4.z : a4.w;
            sv[q * 4 + c] = (v2f){a, a} + tv[q * 4 + c];
          }
        }
        v2f m;
        {
          v2f m0 = __builtin_elementwise_max(sv[0], sv[1]);
          v2f m1 = __builtin_elementwise_max(sv[2], sv[3]);
          v2f m2 = __builtin_elementwise_max(sv[4], sv[5]);
          v2f m3 = __builtin_elementwise_max(sv[6], sv[7]);
          v2f m4 = __builtin_elementwise_max(sv[8], sv[9]);
          v2f m5 = __builtin_elementwise_max(sv[10], sv[11]);
          v2f m6 = __builtin_elementwise_max(sv[12], sv[13]);
          v2f m7 = __builtin_elementwise_max(sv[14], sv[15]);
          m0 = __builtin_elementwise_max(m0, m1);
          m2 = __builtin_elementwise_max(m2, m3);
          m4 = __builtin_elementwise_max(m4, m5);
          m6 = __builtin_elementwise_max(m6, m7);
          m0 = __builtin_elementwise_max(m0, m2);
          m4 = __builtin_elementwise_max(m4, m6);
          m = __builtin_elementwise_max(m0, m4);
        }
        {
          v2f o;
          o.x = dpp_f<0xB1>(m.x); o.y = dpp_f<0xB1>(m.y);
          m = __builtin_elementwise_max(m, o);
          o.x = dpp_f<0x4E>(m.x); o.y = dpp_f<0x4E>(m.y);
          m = __builtin_elementwise_max(m, o);
          o.x = dpp_f<0x141>(m.x); o.y = dpp_f<0x141>(m.y);
          m = __builtin_elementwise_max(m, o);
        }
        int ai0 = 0xFFFF, ai1 = 0xFFFF;
#pragma unroll
        for (int i = 15; i >= 0; --i) {
          ai0 = (sv[i].x == m.x) ? (i0 + i) : ai0;
          ai1 = (sv[i].y == m.y) ? (i0 + i) : ai1;
        }
        int aip = ai0 | (ai1 << 16);
        aip = pkminu16(aip, dpp_i<0xB1>(aip));
        aip = pkminu16(aip, dpp_i<0x4E>(aip));
        aip = pkminu16(aip, dpp_i<0x141>(aip));

        v2f em2 = emC[s];
        if (rg == 0)
          *(v2f*)(av[t & 1] + AIDX(j0)) = m + em2;
        unsigned int pk = ((unsigned int)aip & 0xFFu) |
                          (((unsigned int)aip >> 8) & 0xFF00u);
        unsigned int sh = pk << ((s & 1) * 16);
        if (s < 2) w0 |= sh; else w1 |= sh;
        BARRIER_LGKM();
      }
      pw0 = w0; pw1 = w1; pend_c = (tc - 1) >> 2;
#pragma unroll
      for (int s = 0; s < 4; ++s) emC[s] = emN[s];
    }
    if (pend_c >= 0 && rg == 1) {
      *(uint2*)(bp + (((b << 7) + pend_c) << 9) + (cg << 3)) =
          make_uint2(pw0, pw1);
    }

    const float* avf = av[(L - 1) & 1];
    {
      float v = (tid < KK) ? avf[AIDX(tid)] : -3.4e38f;
      int idx = (tid < KK) ? tid : KK;
#pragma unroll
      for (int mm = 1; mm < 64; mm <<= 1) {
        float ov = __shfl_xor(v, mm);
        int oi = __shfl_xor(idx, mm);
        if (ov > v || (ov == v && oi < idx)) { v = ov; idx = oi; }
      }
      if ((tid & 63) == 0) { rv[tid >> 6] = v; ri[tid >> 6] = idx; }
    }
    __syncthreads();
    if (tid == 0) {
      float bv = rv[0]; int bi = ri[0];
#pragma unroll
      for (int w = 1; w < 8; ++w)
        if (rv[w] > bv || (rv[w] == bv && ri[w] < bi)) { bv = rv[w]; bi = ri[w]; }
      last_s = bi;
    }
    __syncthreads();
    const int last = last_s;
    if (tid >= L - 1 && tid < TT) tags[tid] = (unsigned char)last;
    __syncthreads();

    if (tid < 64 && L >= 2) {
      const uint2* bpv = (const uint2*)bp;
      int tag = last;
      int cTop = (L - 2) >> 2;
      uint2 q = bpv[(((b << 7) + cTop) << 6) + tid];
      for (int c = cTop; c >= 0; --c) {
        uint2 qn;
        if (c > 0) qn = bpv[(((b << 7) + (c - 1)) << 6) + tid];
        int sHi = (L - 2) - 4 * c; if (sHi > 3) sHi = 3;
#pragma unroll
        for (int s = 3; s >= 0; --s) {
          if (s <= sHi) {
            int word = (s < 2) ? (int)q.x : (int)q.y;
            unsigned int w = (unsigned int)__shfl(word, tag >> 1);
            tag = (int)((w >> ((((s & 1) << 1) | (tag & 1)) << 3)) & 255u);
            if (tid == 0) tags[4 * c + s] = (unsigned char)tag;
          }
        }
        q = qn;
      }
    }
    __syncthreads();
    pred_out[b * TT + tid] = (float)tags[tid];

  } else {
    const int b = blockIdx.x - BB;
    const int L = seq_lens[b];
    __shared__ __align__(16) float ev[2][144];
    __shared__ __align__(16) float wmax[16];
    __shared__ float rs[8]; __shared__ float rsc[8];

    v2f tw[16];
#pragma unroll
    for (int ii = 0; ii < 16; ++ii) {
      v2f tr = *(const v2f*)&trans[(i0 + ii) * KK + j0];
      tw[ii].x = __expf(tr.x);
      tw[ii].y = __expf(tr.y);
    }
    if (tid < KK) ev[0][AIDX(tid)] = __expf(logits[(b * TT) * KK + tid]);
    if (tid < 16) wmax[tid] = 1.0f;

    v2f emC[4], emN[4];
#pragma unroll
    for (int s = 0; s < 4; ++s) {
      int t2 = 1 + s; if (t2 > L - 1) t2 = (L > 1) ? (L - 1) : 0;
      emC[s] = *(const v2f*)&logits[(b * TT + t2) * KK + j0];
    }
    __syncthreads();

    float Cln = 0.0f;
    for (int tc = 1; tc < L; tc += 4) {
#pragma unroll
      for (int s = 0; s < 4; ++s) {
        int t2 = tc + 4 + s; if (t2 > L - 1) t2 = L - 1;
        emN[s] = *(const v2f*)&logits[(b * TT + t2) * KK + j0];
      }
      float r;
      {
        float4 w0 = *(const float4*)&wmax[0];
        float4 w1 = *(const float4*)&wmax[4];
        float4 w2 = *(const float4*)&wmax[8];
        float4 w3 = *(const float4*)&wmax[12];
        float U = fmaxf(fmaxf(fmaxf(w0.x, w0.y), fmaxf(w0.z, w0.w)),
                        fmaxf(fmaxf(w1.x, w1.y), fmaxf(w1.z, w1.w)));
        U = fmaxf(U, fmaxf(fmaxf(fmaxf(w2.x, w2.y), fmaxf(w2.z, w2.w)),
                           fmaxf(fmaxf(w3.x, w3.y), fmaxf(w3.z, w3.w))));
        int ex = (__float_as_int(U) >> 23) & 255;
        r = __int_as_float((254 - ex) << 23);
        Cln += (float)(ex - 127) * 0.6931471805599453f;
      }
#pragma unroll
      for (int s = 0; s < 4; ++s) {
        const int t = tc + s;
        if (t >= L) break;
        const float4* evr = (const float4*)(ev[(t & 1) ^ 1] + AIDX(i0));
        v2f S2 = {0.0f, 0.0f};
#pragma unroll
        for (int q = 0; q < 4; ++q) {
          float4 e4 = evr[q];
#pragma unroll
          for (int c = 0; c < 4; ++c) {
            float e = (c == 0) ? e4.x : (c == 1) ? e4.y : (c == 2) ? e4.z : e4.w;
            S2 += (v2f){e, e} * tw[q * 4 + c];
          }
        }
        {
          v2f o;
          o.x = dpp_f<0xB1>(S2.x); o.y = dpp_f<0xB1>(S2.y); S2 += o;
          o.x = dpp_f<0x4E>(S2.x); o.y = dpp_f<0x4E>(S2.y); S2 += o;
          o.x = dpp_f<0x141>(S2.x); o.y = dpp_f<0x141>(S2.y); S2 += o;
        }
        v2f em2 = emC[s];
        float evn0 = S2.x * __expf(em2.x);
        float evn1 = S2.y * __expf(em2.y);
        if (s == 0) { evn0 *= r; evn1 *= r; }
        if (rg == 0)
          *(v2f*)(ev[t & 1] + AIDX(j0)) = (v2f){evn0, evn1};
        if (s == 3) {
          float wmx = fmaxf(evn0, evn1);
          wmx = fmaxf(wmx, dpp_f<0x140>(wmx));
          wmx = fmaxf(wmx, swz16_f(wmx));
          if ((tid & 31) == 0) wmax[tid >> 5] = wmx;
        }
        BARRIER_LGKM();
      }
#pragma unroll
      for (int s = 0; s < 4; ++s) emC[s] = emN[s];
    }

    const float* evf = ev[(L - 1) & 1];
    {
      float ssum = (tid < KK) ? evf[AIDX(tid)] : 0.0f;
#pragma unroll
      for (int mm = 1; mm < 64; mm <<= 1) ssum += __shfl_xor(ssum, mm);
      if ((tid & 63) == 0) rs[tid >> 6] = ssum;
    }
    float sc = 0.0f;
    for (int tt2 = tid; tt2 < L; tt2 += 512) {
      int lab = labels[b * TT + tt2];
      sc += logits[(b * TT + tt2) * KK + lab];
      if (tt2 >= 1) sc += trans[labels[b * TT + tt2 - 1] * KK + lab];
    }
#pragma unroll
    for (int mm = 1; mm < 64; mm <<= 1) sc += __shfl_xor(sc, mm);
    if ((tid & 63) == 0) rsc[tid >> 6] = sc;
    __syncthreads();
    if (tid == 0) {
      float es = rs[0]; float scf = rsc[0];
#pragma unroll
      for (int w = 1; w < 8; ++w) { es += rs[w]; scf += rsc[w]; }
      negll[b] = (Cln + logf(es)) - scf;
    }
  }
}

__global__ void crf_loss_reduce(const float* __restrict__ negll, float* __restrict__ out) {
  int tid = threadIdx.x;
  float v = negll[tid];
#pragma unroll
  for (int m = 1; m < 64; m <<= 1) v += __shfl_xor(v, m);
  __shared__ float p[4];
  if ((tid & 63) == 0) p[tid >> 6] = v;
  __syncthreads();
  if (tid == 0) out[0] = p[0] + p[1] + p[2] + p[3];
}

extern "C" void kernel_launch(void* const* d_in, const int* in_sizes, int n_in,
                              void* d_out, int out_size, void* d_ws, size_t ws_size,
                              hipStream_t stream) {
  const float* logits   = (const float*)d_in[0];
  const int*   labels   = (const int*)d_in[1];
  const int*   seq_lens = (const int*)d_in[2];
  const float* trans    = (const float*)d_in[3];
  float* out = (float*)d_out;

  float* negll = (float*)d_ws;                          // [0, 1KB): 256 floats
  const size_t M_OFF = 4096;
  const size_t NEED = M_OFF + (size_t)BB * TT * KK * 4;   // ~67.1 MB

  if (ws_size >= NEED) {
    float* mOut = (float*)((char*)d_ws + M_OFF);        // [4KB, 4KB+67.1MB)
    crf_wave<<<2 * BB, 64, 0, stream>>>(logits, labels, seq_lens, trans,
                                        out + 1, negll, mOut);
  } else {
    unsigned char* bp = (unsigned char*)d_ws + 1024;    // 16.8 MB
    crf_main_fb<<<2 * BB, 512, 0, stream>>>(logits, labels, seq_lens, trans,
                                            out + 1, negll, bp);
  }
  crf_loss_reduce<<<1, 256, 0, stream>>>(negll, out);
}

// Round 12
// 816.696 us; speedup vs baseline: 1.1431x; 1.1431x over previous
//
#include <hip/hip_runtime.h>
#include <math.h>

#define BB 256
#define TT 512
#define KK 128

// smem layout (float indices) for crf_pair — 34304 floats = 137.2 KB, 1 block/CU
#define SW_TT    0                     // [128][130] transposed trans (chase)
#define SW_TRM   16640                 // vit hi rows T[64..127] row-major [64][130]
#define SW_ETRM  24960                 // fwd hi rows exp(T)[64..127] [64][130]
#define SW_AV    33280                 // vit alpha double buffer [2][128]
#define SW_AF    33536                 // fwd alpha double buffer [2][128]
#define SW_TAGS  33792                 // tagsf[512]
#define SW_TOTAL 34304

typedef float v2f __attribute__((ext_vector_type(2)));

#define REP64(M) M(0) M(1) M(2) M(3) M(4) M(5) M(6) M(7) M(8) M(9) M(10) M(11) \
  M(12) M(13) M(14) M(15) M(16) M(17) M(18) M(19) M(20) M(21) M(22) M(23)      \
  M(24) M(25) M(26) M(27) M(28) M(29) M(30) M(31) M(32) M(33) M(34) M(35)      \
  M(36) M(37) M(38) M(39) M(40) M(41) M(42) M(43) M(44) M(45) M(46) M(47)      \
  M(48) M(49) M(50) M(51) M(52) M(53) M(54) M(55) M(56) M(57) M(58) M(59)      \
  M(60) M(61) M(62) M(63)

// ============================================================================
// crf_pair: one 128-thread block per sequence. Wave 0 = viterbi, wave 1 =
// forward log-norm. Waves share NOTHING -> zero barriers. Per lane: 2 cols;
// T rows 0-63 in 64 NAMED v2f registers (128 VGPRs, under the 256 cap),
// rows 64-127 from padded LDS row-major copy; alpha via broadcast b128.
// Wave 0 then runs the verified equality-match chase.
// ============================================================================
__global__ __launch_bounds__(128, 1) void crf_pair(
    const float* __restrict__ logits,     // [B,T,K]
    const int* __restrict__ labels,       // [B,T]
    const int* __restrict__ seq_lens,     // [B]
    const float* __restrict__ trans,      // [K,K]
    float* __restrict__ pred_out,         // [B,T] as float (d_out+1)
    float* __restrict__ negll,            // [B] in ws
    float* __restrict__ mOut)             // [B][T][K] in ws (t>=1 valid)
{
  __shared__ __align__(16) float smem[SW_TOTAL];
  float* tT    = smem + SW_TT;
  float* Trm   = smem + SW_TRM;
  float* eTrm  = smem + SW_ETRM;
  float* aV    = smem + SW_AV;
  float* aF    = smem + SW_AF;
  float* tagsf = smem + SW_TAGS;

  const int tid = threadIdx.x;
  const int l = tid & 63;
  const int j0 = 2 * l;
  const int b = blockIdx.x;
  const int L = seq_lens[b];
  const float* lg = logits + (size_t)b * TT * KK;

  if (tid < 64) {
    // ========================= VITERBI WAVE =========================
    // build transposed trans for the chase
    for (int e4 = l; e4 < (KK * KK) / 4; e4 += 64) {
      float4 v = ((const float4*)trans)[e4];
      int i = e4 >> 5;              // row (32 float4 per row)
      int j = (e4 & 31) * 4;        // col base
      tT[(j + 0) * 130 + i] = v.x;
      tT[(j + 1) * 130 + i] = v.y;
      tT[(j + 2) * 130 + i] = v.z;
      tT[(j + 3) * 130 + i] = v.w;
    }
    // build row-major hi rows [64][130]
    for (int e4 = l; e4 < 64 * 32; e4 += 64) {
      int i = 64 + (e4 >> 5);
      int c = (e4 & 31) * 4;
      float4 v = *(const float4*)&trans[i * KK + c];
      *(float4*)&Trm[(i - 64) * 130 + c] = v;
    }
    // T rows 0..63 for this lane's two columns: NAMED registers
#define TVLOAD(I) v2f tv##I = *(const v2f*)&trans[(I) * KK + j0];
    REP64(TVLOAD)
#undef TVLOAD

    v2f afin = *(const v2f*)&lg[j0];    // alpha_0 for own cols
    *(v2f*)&aV[0 * 128 + j0] = afin;

    v2f emC[4], emN[4];
#pragma unroll
    for (int s = 0; s < 4; ++s) {
      int t2 = 1 + s; if (t2 > L - 1) t2 = (L > 1) ? (L - 1) : 0;
      emC[s] = *(const v2f*)&lg[t2 * KK + j0];
    }

    for (int tc = 1; tc < L; tc += 4) {
#pragma unroll
      for (int s = 0; s < 4; ++s) {
        int t2 = tc + 4 + s; if (t2 > L - 1) t2 = L - 1;
        emN[s] = *(const v2f*)&lg[t2 * KK + j0];
      }
#pragma unroll
      for (int s = 0; s < 4; ++s) {
        const int t = tc + s;
        if (t >= L) break;
        const float4* ap = (const float4*)&aV[((t & 1) ^ 1) * 128];
        // hi rows 64..127 from LDS (issue loads early)
        v2f bestH = {-3.4e38f, -3.4e38f};
#pragma unroll
        for (int q = 0; q < 16; ++q) {
          float4 a4 = ap[16 + q];
          v2f h0 = *(const v2f*)&Trm[(4 * q + 0) * 130 + j0];
          v2f h1 = *(const v2f*)&Trm[(4 * q + 1) * 130 + j0];
          v2f h2 = *(const v2f*)&Trm[(4 * q + 2) * 130 + j0];
          v2f h3 = *(const v2f*)&Trm[(4 * q + 3) * 130 + j0];
          v2f y0 = (v2f){a4.x, a4.x} + h0;   // exact IEEE adds
          v2f y1 = (v2f){a4.y, a4.y} + h1;
          v2f y2 = (v2f){a4.z, a4.z} + h2;
          v2f y3 = (v2f){a4.w, a4.w} + h3;
          bestH = __builtin_elementwise_max(bestH,
              __builtin_elementwise_max(
                  __builtin_elementwise_max(y0, y1),
                  __builtin_elementwise_max(y2, y3)));
        }
        // low rows 0..63 from registers
        v2f bestL = {-3.4e38f, -3.4e38f};
#define ACC4(Q, A, Bq, C, D)                                   \
        { float4 a4 = ap[Q];                                   \
          v2f x0 = (v2f){a4.x, a4.x} + tv##A;                  \
          v2f x1 = (v2f){a4.y, a4.y} + tv##Bq;                 \
          v2f x2 = (v2f){a4.z, a4.z} + tv##C;                  \
          v2f x3 = (v2f){a4.w, a4.w} + tv##D;                  \
          bestL = __builtin_elementwise_max(bestL,             \
              __builtin_elementwise_max(                       \
                  __builtin_elementwise_max(x0, x1),           \
                  __builtin_elementwise_max(x2, x3))); }
        ACC4(0,0,1,2,3)    ACC4(1,4,5,6,7)    ACC4(2,8,9,10,11)
        ACC4(3,12,13,14,15) ACC4(4,16,17,18,19) ACC4(5,20,21,22,23)
        ACC4(6,24,25,26,27) ACC4(7,28,29,30,31) ACC4(8,32,33,34,35)
        ACC4(9,36,37,38,39) ACC4(10,40,41,42,43) ACC4(11,44,45,46,47)
        ACC4(12,48,49,50,51) ACC4(13,52,53,54,55) ACC4(14,56,57,58,59)
        ACC4(15,60,61,62,63)
#undef ACC4
        v2f m = __builtin_elementwise_max(bestL, bestH);   // full 128-row max
        v2f nav = m + emC[s];
        afin = nav;
        *(v2f*)&aV[(t & 1) * 128 + j0] = nav;              // same-wave publish
        *(v2f*)&mOut[(size_t)(b * TT + t) * KK + j0] = m;  // coalesced 512B
      }
#pragma unroll
      for (int s = 0; s < 4; ++s) emC[s] = emN[s];
    }

    // final argmax across K (first-index ties)
    int last;
    {
      float v; int idx;
      if (afin.x >= afin.y) { v = afin.x; idx = j0; }
      else                  { v = afin.y; idx = j0 + 1; }
#pragma unroll
      for (int mm = 1; mm < 64; mm <<= 1) {
        float ov = __shfl_xor(v, mm);
        int oi = __shfl_xor(idx, mm);
        if (ov > v || (ov == v && oi < idx)) { v = ov; idx = oi; }
      }
      last = idx;
    }
    for (int t2 = l; t2 < TT; t2 += 64) tagsf[t2] = (float)last;
    // drain mOut stores before same-wave re-read in the chase
    asm volatile("s_waitcnt vmcnt(0) lgkmcnt(0)" ::: "memory");

    // ============ equality-match chase (verified, verbatim) ==========
    if (L >= 2) {
      const float* mb = mOut + (size_t)(b * TT) * KK + j0;
      const float* gb = lg + j0;
      int tag = last;
      v2f mvC = *(const v2f*)&mb[(size_t)(L - 1) * KK];

      v2f lg0, lg1, lg2, lg3, lg4, lg5, lg6, lg7;
      v2f mv0, mv1, mv2, mv3, mv4, mv5, mv6, mv7;
#define INITLD(PP) { int s_ = L - 2 - (PP); int sc_ = s_ < 0 ? 0 : s_;         \
      lg##PP = *(const v2f*)&gb[(size_t)sc_ * KK];                             \
      mv##PP = *(const v2f*)&mb[(size_t)sc_ * KK]; }
      INITLD(0) INITLD(1) INITLD(2) INITLD(3)
      INITLD(4) INITLD(5) INITLD(6) INITLD(7)
#undef INITLD

      int t = L - 1;

#define STEP_BODY(LG, MV, GUARDED)                                             \
      {                                                                        \
        const int tp = t - 1;                                                  \
        v2f aP;                                                                \
        if (GUARDED) aP = (tp >= 1) ? (MV + LG) : LG;                          \
        else         aP = MV + LG;                                             \
        int lanem = tag >> 1;                                                  \
        int txi = __builtin_amdgcn_readlane(__float_as_int(mvC.x), lanem);     \
        int tyi = __builtin_amdgcn_readlane(__float_as_int(mvC.y), lanem);     \
        float target = __int_as_float((tag & 1) ? tyi : txi);                  \
        v2f col = *(const v2f*)&tT[tag * 130 + j0];                            \
        v2f sv = aP + col;                                                     \
        bool h0 = (sv.x == target), h1 = (sv.y == target);                     \
        unsigned long long mask = __ballot(h0 || h1);                          \
        int first = __ffsll(mask) - 1;                                         \
        int cand = h0 ? j0 : (j0 + 1);                                         \
        tag = __builtin_amdgcn_readlane(cand, first);                          \
        if (l == 0) tagsf[tp] = (float)tag;                                    \
        mvC = MV;                                                              \
      }

      while (t >= 9) {
#define MAIN_PHASE(PP)                                                         \
        STEP_BODY(lg##PP, mv##PP, false)                                       \
        { int sN = t - 9; int sc_ = sN < 0 ? 0 : sN;                           \
          lg##PP = *(const v2f*)&gb[(size_t)sc_ * KK];                         \
          mv##PP = *(const v2f*)&mb[(size_t)sc_ * KK]; }                       \
        --t;
        MAIN_PHASE(0) MAIN_PHASE(1) MAIN_PHASE(2) MAIN_PHASE(3)
        MAIN_PHASE(4) MAIN_PHASE(5) MAIN_PHASE(6) MAIN_PHASE(7)
#undef MAIN_PHASE
      }
      while (t >= 1) {
        const int tp = t - 1;
        int sc_ = tp < 1 ? 0 : tp;
        v2f lgE = *(const v2f*)&gb[(size_t)tp * KK];
        v2f mvE = *(const v2f*)&mb[(size_t)sc_ * KK];
        STEP_BODY(lgE, mvE, true)
        --t;
      }
#undef STEP_BODY
    }
#pragma unroll
    for (int k = 0; k < 8; ++k)
      pred_out[b * TT + l * 8 + k] = tagsf[l * 8 + k];

  } else {
    // ========================= FORWARD WAVE =========================
    // build exp'd hi rows [64][130]
    for (int e4 = l; e4 < 64 * 32; e4 += 64) {
      int i = 64 + (e4 >> 5);
      int c = (e4 & 31) * 4;
      float4 v = *(const float4*)&trans[i * KK + c];
      float4 w;
      w.x = __expf(v.x); w.y = __expf(v.y);
      w.z = __expf(v.z); w.w = __expf(v.w);
      *(float4*)&eTrm[(i - 64) * 130 + c] = w;
    }
#define TWLOAD(I) v2f tw##I;                                                   \
    { v2f tr = *(const v2f*)&trans[(I) * KK + j0];                             \
      tw##I.x = __expf(tr.x); tw##I.y = __expf(tr.y); }
    REP64(TWLOAD)
#undef TWLOAD

    v2f efin;
    efin.x = __expf(lg[j0]);
    efin.y = __expf(lg[j0 + 1]);
    *(v2f*)&aF[0 * 128 + j0] = efin;
    float wm = 1.0f;

    v2f emC[4], emN[4];
#pragma unroll
    for (int s = 0; s < 4; ++s) {
      int t2 = 1 + s; if (t2 > L - 1) t2 = (L > 1) ? (L - 1) : 0;
      emC[s] = *(const v2f*)&lg[t2 * KK + j0];
    }

    float Cln = 0.0f;
    for (int tc = 1; tc < L; tc += 4) {
#pragma unroll
      for (int s = 0; s < 4; ++s) {
        int t2 = tc + 4 + s; if (t2 > L - 1) t2 = L - 1;
        emN[s] = *(const v2f*)&lg[t2 * KK + j0];
      }
      float r;
      {
        int ex = (__float_as_int(wm) >> 23) & 255;
        r = __int_as_float((254 - ex) << 23);
        Cln += (float)(ex - 127) * 0.6931471805599453f;
      }
#pragma unroll
      for (int s = 0; s < 4; ++s) {
        const int t = tc + s;
        if (t >= L) break;
        const float4* ep = (const float4*)&aF[((t & 1) ^ 1) * 128];
        v2f S0 = {0.0f, 0.0f}, S1 = {0.0f, 0.0f};
        v2f S2v = {0.0f, 0.0f}, S3 = {0.0f, 0.0f};
        // hi rows from LDS
#pragma unroll
        for (int q = 0; q < 16; ++q) {
          float4 a4 = ep[16 + q];
          v2f h0 = *(const v2f*)&eTrm[(4 * q + 0) * 130 + j0];
          v2f h1 = *(const v2f*)&eTrm[(4 * q + 1) * 130 + j0];
          v2f h2 = *(const v2f*)&eTrm[(4 * q + 2) * 130 + j0];
          v2f h3 = *(const v2f*)&eTrm[(4 * q + 3) * 130 + j0];
          S0 += (v2f){a4.x, a4.x} * h0;   // pk_fma
          S1 += (v2f){a4.y, a4.y} * h1;
          S2v += (v2f){a4.z, a4.z} * h2;
          S3 += (v2f){a4.w, a4.w} * h3;
        }
        // low rows from registers
#define ACC4F(Q, A, Bq, C, D)                                  \
        { float4 a4 = ep[Q];                                   \
          S0 += (v2f){a4.x, a4.x} * tw##A;                     \
          S1 += (v2f){a4.y, a4.y} * tw##Bq;                    \
          S2v += (v2f){a4.z, a4.z} * tw##C;                    \
          S3 += (v2f){a4.w, a4.w} * tw##D; }
        ACC4F(0,0,1,2,3)    ACC4F(1,4,5,6,7)    ACC4F(2,8,9,10,11)
        ACC4F(3,12,13,14,15) ACC4F(4,16,17,18,19) ACC4F(5,20,21,22,23)
        ACC4F(6,24,25,26,27) ACC4F(7,28,29,30,31) ACC4F(8,32,33,34,35)
        ACC4F(9,36,37,38,39) ACC4F(10,40,41,42,43) ACC4F(11,44,45,46,47)
        ACC4F(12,48,49,50,51) ACC4F(13,52,53,54,55) ACC4F(14,56,57,58,59)
        ACC4F(15,60,61,62,63)
#undef ACC4F
        v2f S = (S0 + S1) + (S2v + S3);
        v2f em2 = emC[s];
        float evn0 = S.x * __expf(em2.x);
        float evn1 = S.y * __expf(em2.y);
        if (s == 0) { evn0 *= r; evn1 *= r; }
        efin = (v2f){evn0, evn1};
        *(v2f*)&aF[(t & 1) * 128 + j0] = efin;
        if (s == 3) {
          float t0 = fmaxf(evn0, evn1);
#pragma unroll
          for (int mm = 1; mm < 64; mm <<= 1) t0 = fmaxf(t0, __shfl_xor(t0, mm));
          wm = t0;
        }
      }
#pragma unroll
      for (int s = 0; s < 4; ++s) emC[s] = emN[s];
    }

    float es;
    {
      float ssum = efin.x + efin.y;
#pragma unroll
      for (int mm = 1; mm < 64; mm <<= 1) ssum += __shfl_xor(ssum, mm);
      es = ssum;
    }
    float sc = 0.0f;
    for (int tt2 = l; tt2 < L; tt2 += 64) {
      int lab = labels[b * TT + tt2];
      sc += lg[tt2 * KK + lab];
      if (tt2 >= 1) sc += trans[labels[b * TT + tt2 - 1] * KK + lab];
    }
#pragma unroll
    for (int mm = 1; mm < 64; mm <<= 1) sc += __shfl_xor(sc, mm);
    if (l == 0) negll[b] = (Cln + logf(es)) - sc;
  }
}

// ============================================================================
// FALLBACK: verbatim 438us two-block kernel (bp in ws), used if ws too small.
// ============================================================================
#define AIDX(i) ((i) + (((i) >> 5) << 2))
typedef unsigned short u16v2 __attribute__((ext_vector_type(2)));
template<int CTRL>
__device__ __forceinline__ int dpp_i(int x) {
  return __builtin_amdgcn_update_dpp(x, x, CTRL, 0xF, 0xF, true);
}
template<int CTRL>
__device__ __forceinline__ float dpp_f(float x) {
  return __int_as_float(dpp_i<CTRL>(__float_as_int(x)));
}
__device__ __forceinline__ float swz16_f(float x) {
  return __int_as_float(__builtin_amdgcn_ds_swizzle(__float_as_int(x), 0x401F));
}
__device__ __forceinline__ int pkminu16(int a, int b) {
  u16v2 av = *(u16v2*)&a, bv = *(u16v2*)&b;
  u16v2 r = __builtin_elementwise_min(av, bv);
  return *(int*)&r;
}
#define BARRIER_LGKM() asm volatile("s_waitcnt lgkmcnt(0)\ns_barrier" ::: "memory")

__global__ __launch_bounds__(512, 4) void crf_main_fb(
    const float* __restrict__ logits,
    const int* __restrict__ labels,
    const int* __restrict__ seq_lens,
    const float* __restrict__ trans,
    float* __restrict__ pred_out,
    float* __restrict__ negll,
    unsigned char* __restrict__ bp)
{
  const int tid = threadIdx.x;
  const int cg = tid >> 3, rg = tid & 7;
  const int j0 = cg * 2, i0 = rg * 16;

  if (blockIdx.x < BB) {
    const int b = blockIdx.x;
    const int L = seq_lens[b];
    __shared__ __align__(16) float av[2][144];
    __shared__ unsigned char tags[TT];
    __shared__ float rv[8]; __shared__ int ri[8];
    __shared__ int last_s;

    v2f tv[16];
#pragma unroll
    for (int ii = 0; ii < 16; ++ii)
      tv[ii] = *(const v2f*)&trans[(i0 + ii) * KK + j0];

    if (tid < KK) av[0][AIDX(tid)] = logits[(b * TT) * KK + tid];

    v2f emC[4], emN[4];
#pragma unroll
    for (int s = 0; s < 4; ++s) {
      int t2 = 1 + s; if (t2 > L - 1) t2 = (L > 1) ? (L - 1) : 0;
      emC[s] = *(const v2f*)&logits[(b * TT + t2) * KK + j0];
    }
    __syncthreads();

    unsigned int pw0 = 0, pw1 = 0; int pend_c = -1;

    for (int tc = 1; tc < L; tc += 4) {
#pragma unroll
      for (int s = 0; s < 4; ++s) {
        int t2 = tc + 4 + s; if (t2 > L - 1) t2 = L - 1;
        emN[s] = *(const v2f*)&logits[(b * TT + t2) * KK + j0];
      }
      if (pend_c >= 0 && rg == 1) {
        *(uint2*)(bp + (((b << 7) + pend_c) << 9) + (cg << 3)) =
            make_uint2(pw0, pw1);
      }
      unsigned int w0 = 0, w1 = 0;
#pragma unroll
      for (int s = 0; s < 4; ++s) {
        const int t = tc + s;
        if (t >= L) break;
        const float4* avr = (const float4*)(av[(t & 1) ^ 1] + AIDX(i0));
        v2f sv[16];
#pragma unroll
        for (int q = 0; q < 4; ++q) {
          float4 a4 = avr[q];
#pragma unroll
          for (int c = 0; c < 4; ++c) {
            float a = (c == 0) ? a4.x : (c == 1) ? a4.y : (c == 2) ? a4.z : a4.w;
            sv[q * 4 + c] = (v2f){a, a} + tv[q * 4 + c];
          }
        }
        v2f m;
        {
          v2f m0 = __builtin_elementwise_max(sv[0], sv[1]);
          v2f m1 = __builtin_elementwise_max(sv[2], sv[3]);
          v2f m2 = __builtin_elementwise_max(sv[4], sv[5]);
          v2f m3 = __builtin_elementwise_max(sv[6], sv[7]);
          v2f m4 = __builtin_elementwise_max(sv[8], sv[9]);
          v2f m5 = __builtin_elementwise_max(sv[10], sv[11]);
          v2f m6 = __builtin_elementwise_max(sv[12], sv[13]);
          v2f m7 = __builtin_elementwise_max(sv[14], sv[15]);
          m0 = __builtin_elementwise_max(m0, m1);
          m2 = __builtin_elementwise_max(m2, m3);
          m4 = __builtin_elementwise_max(m4, m5);
          m6 = __builtin_elementwise_max(m6, m7);
          m0 = __builtin_elementwise_max(m0, m2);
          m4 = __builtin_elementwise_max(m4, m6);
          m = __builtin_elementwise_max(m0, m4);
        }
        {
          v2f o;
          o.x = dpp_f<0xB1>(m.x); o.y = dpp_f<0xB1>(m.y);
          m = __builtin_elementwise_max(m, o);
          o.x = dpp_f<0x4E>(m.x); o.y = dpp_f<0x4E>(m.y);
          m = __builtin_elementwise_max(m, o);
          o.x = dpp_f<0x141>(m.x); o.y = dpp_f<0x141>(m.y);
          m = __builtin_elementwise_max(m, o);
        }
        int ai0 = 0xFFFF, ai1 = 0xFFFF;
#pragma unroll
        for (int i = 15; i >= 0; --i) {
          ai0 = (sv[i].x == m.x) ? (i0 + i) : ai0;
          ai1 = (sv[i].y == m.y) ? (i0 + i) : ai1;
        }
        int aip = ai0 | (ai1 << 16);
        aip = pkminu16(aip, dpp_i<0xB1>(aip));
        aip = pkminu16(aip, dpp_i<0x4E>(aip));
        aip = pkminu16(aip, dpp_i<0x141>(aip));

        v2f em2 = emC[s];
        if (rg == 0)
          *(v2f*)(av[t & 1] + AIDX(j0)) = m + em2;
        unsigned int pk = ((unsigned int)aip & 0xFFu) |
                          (((unsigned int)aip >> 8) & 0xFF00u);
        unsigned int sh = pk << ((s & 1) * 16);
        if (s < 2) w0 |= sh; else w1 |= sh;
        BARRIER_LGKM();
      }
      pw0 = w0; pw1 = w1; pend_c = (tc - 1) >> 2;
#pragma unroll
      for (int s = 0; s < 4; ++s) emC[s] = emN[s];
    }
    if (pend_c >= 0 && rg == 1) {
      *(uint2*)(bp + (((b << 7) + pend_c) << 9) + (cg << 3)) =
          make_uint2(pw0, pw1);
    }

    const float* avf = av[(L - 1) & 1];
    {
      float v = (tid < KK) ? avf[AIDX(tid)] : -3.4e38f;
      int idx = (tid < KK) ? tid : KK;
#pragma unroll
      for (int mm = 1; mm < 64; mm <<= 1) {
        float ov = __shfl_xor(v, mm);
        int oi = __shfl_xor(idx, mm);
        if (ov > v || (ov == v && oi < idx)) { v = ov; idx = oi; }
      }
      if ((tid & 63) == 0) { rv[tid >> 6] = v; ri[tid >> 6] = idx; }
    }
    __syncthreads();
    if (tid == 0) {
      float bv = rv[0]; int bi = ri[0];
#pragma unroll
      for (int w = 1; w < 8; ++w)
        if (rv[w] > bv || (rv[w] == bv && ri[w] < bi)) { bv = rv[w]; bi = ri[w]; }
      last_s = bi;
    }
    __syncthreads();
    const int last = last_s;
    if (tid >= L - 1 && tid < TT) tags[tid] = (unsigned char)last;
    __syncthreads();

    if (tid < 64 && L >= 2) {
      const uint2* bpv = (const uint2*)bp;
      int tag = last;
      int cTop = (L - 2) >> 2;
      uint2 q = bpv[(((b << 7) + cTop) << 6) + tid];
      for (int c = cTop; c >= 0; --c) {
        uint2 qn;
        if (c > 0) qn = bpv[(((b << 7) + (c - 1)) << 6) + tid];
        int sHi = (L - 2) - 4 * c; if (sHi > 3) sHi = 3;
#pragma unroll
        for (int s = 3; s >= 0; --s) {
          if (s <= sHi) {
            int word = (s < 2) ? (int)q.x : (int)q.y;
            unsigned int w = (unsigned int)__shfl(word, tag >> 1);
            tag = (int)((w >> ((((s & 1) << 1) | (tag & 1)) << 3)) & 255u);
            if (tid == 0) tags[4 * c + s] = (unsigned char)tag;
          }
        }
        q = qn;
      }
    }
    __syncthreads();
    pred_out[b * TT + tid] = (float)tags[tid];

  } else {
    const int b = blockIdx.x - BB;
    const int L = seq_lens[b];
    __shared__ __align__(16) float ev[2][144];
    __shared__ __align__(16) float wmax[16];
    __shared__ float rs[8]; __shared__ float rsc[8];

    v2f tw[16];
#pragma unroll
    for (int ii = 0; ii < 16; ++ii) {
      v2f tr = *(const v2f*)&trans[(i0 + ii) * KK + j0];
      tw[ii].x = __expf(tr.x);
      tw[ii].y = __expf(tr.y);
    }
    if (tid < KK) ev[0][AIDX(tid)] = __expf(logits[(b * TT) * KK + tid]);
    if (tid < 16) wmax[tid] = 1.0f;

    v2f emC[4], emN[4];
#pragma unroll
    for (int s = 0; s < 4; ++s) {
      int t2 = 1 + s; if (t2 > L - 1) t2 = (L > 1) ? (L - 1) : 0;
      emC[s] = *(const v2f*)&logits[(b * TT + t2) * KK + j0];
    }
    __syncthreads();

    float Cln = 0.0f;
    for (int tc = 1; tc < L; tc += 4) {
#pragma unroll
      for (int s = 0; s < 4; ++s) {
        int t2 = tc + 4 + s; if (t2 > L - 1) t2 = L - 1;
        emN[s] = *(const v2f*)&logits[(b * TT + t2) * KK + j0];
      }
      float r;
      {
        float4 w0 = *(const float4*)&wmax[0];
        float4 w1 = *(const float4*)&wmax[4];
        float4 w2 = *(const float4*)&wmax[8];
        float4 w3 = *(const float4*)&wmax[12];
        float U = fmaxf(fmaxf(fmaxf(w0.x, w0.y), fmaxf(w0.z, w0.w)),
                        fmaxf(fmaxf(w1.x, w1.y), fmaxf(w1.z, w1.w)));
        U = fmaxf(U, fmaxf(fmaxf(fmaxf(w2.x, w2.y), fmaxf(w2.z, w2.w)),
                           fmaxf(fmaxf(w3.x, w3.y), fmaxf(w3.z, w3.w))));
        int ex = (__float_as_int(U) >> 23) & 255;
        r = __int_as_float((254 - ex) << 23);
        Cln += (float)(ex - 127) * 0.6931471805599453f;
      }
#pragma unroll
      for (int s = 0; s < 4; ++s) {
        const int t = tc + s;
        if (t >= L) break;
        const float4* evr = (const float4*)(ev[(t & 1) ^ 1] + AIDX(i0));
        v2f S2 = {0.0f, 0.0f};
#pragma unroll
        for (int q = 0; q < 4; ++q) {
          float4 e4 = evr[q];
#pragma unroll
          for (int c = 0; c < 4; ++c) {
            float e = (c == 0) ? e4.x : (c == 1) ? e4.y : (c == 2) ? e4.z : e4.w;
            S2 += (v2f){e, e} * tw[q * 4 + c];
          }
        }
        {
          v2f o;
          o.x = dpp_f<0xB1>(S2.x); o.y = dpp_f<0xB1>(S2.y); S2 += o;
          o.x = dpp_f<0x4E>(S2.x); o.y = dpp_f<0x4E>(S2.y); S2 += o;
          o.x = dpp_f<0x141>(S2.x); o.y = dpp_f<0x141>(S2.y); S2 += o;
        }
        v2f em2 = emC[s];
        float evn0 = S2.x * __expf(em2.x);
        float evn1 = S2.y * __expf(em2.y);
        if (s == 0) { evn0 *= r; evn1 *= r; }
        if (rg == 0)
          *(v2f*)(ev[t & 1] + AIDX(j0)) = (v2f){evn0, evn1};
        if (s == 3) {
          float wmx = fmaxf(evn0, evn1);
          wmx = fmaxf(wmx, dpp_f<0x140>(wmx));
          wmx = fmaxf(wmx, swz16_f(wmx));
          if ((tid & 31) == 0) wmax[tid >> 5] = wmx;
        }
        BARRIER_LGKM();
      }
#pragma unroll
      for (int s = 0; s < 4; ++s) emC[s] = emN[s];
    }

    const float* evf = ev[(L - 1) & 1];
    {
      float ssum = (tid < KK) ? evf[AIDX(tid)] : 0.0f;
#pragma unroll
      for (int mm = 1; mm < 64; mm <<= 1) ssum += __shfl_xor(ssum, mm);
      if ((tid & 63) == 0) rs[tid >> 6] = ssum;
    }
    float sc = 0.0f;
    for (int tt2 = tid; tt2 < L; tt2 += 512) {
      int lab = labels[b * TT + tt2];
      sc += logits[(b * TT + tt2) * KK + lab];
      if (tt2 >= 1) sc += trans[labels[b * TT + tt2 - 1] * KK + lab];
    }
#pragma unroll
    for (int mm = 1; mm < 64; mm <<= 1) sc += __shfl_xor(sc, mm);
    if ((tid & 63) == 0) rsc[tid >> 6] = sc;
    __syncthreads();
    if (tid == 0) {
      float es = rs[0]; float scf = rsc[0];
#pragma unroll
      for (int w = 1; w < 8; ++w) { es += rs[w]; scf += rsc[w]; }
      negll[b] = (Cln + logf(es)) - scf;
    }
  }
}

__global__ void crf_loss_reduce(const float* __restrict__ negll, float* __restrict__ out) {
  int tid = threadIdx.x;
  float v = negll[tid];
#pragma unroll
  for (int m = 1; m < 64; m <<= 1) v += __shfl_xor(v, m);
  __shared__ float p[4];
  if ((tid & 63) == 0) p[tid >> 6] = v;
  __syncthreads();
  if (tid == 0) out[0] = p[0] + p[1] + p[2] + p[3];
}

extern "C" void kernel_launch(void* const* d_in, const int* in_sizes, int n_in,
                              void* d_out, int out_size, void* d_ws, size_t ws_size,
                              hipStream_t stream) {
  const float* logits   = (const float*)d_in[0];
  const int*   labels   = (const int*)d_in[1];
  const int*   seq_lens = (const int*)d_in[2];
  const float* trans    = (const float*)d_in[3];
  float* out = (float*)d_out;

  float* negll = (float*)d_ws;                          // [0, 1KB): 256 floats
  const size_t M_OFF = 4096;
  const size_t NEED = M_OFF + (size_t)BB * TT * KK * 4;   // ~67.1 MB

  if (ws_size >= NEED) {
    float* mOut = (float*)((char*)d_ws + M_OFF);        // [4KB, 4KB+67.1MB)
    crf_pair<<<BB, 128, 0, stream>>>(logits, labels, seq_lens, trans,
                                     out + 1, negll, mOut);
  } else {
    unsigned char* bp = (unsigned char*)d_ws + 1024;    // 16.8 MB
    crf_main_fb<<<2 * BB, 512, 0, stream>>>(logits, labels, seq_lens, trans,
                                            out + 1, negll, bp);
  }
  crf_loss_reduce<<<1, 256, 0, stream>>>(negll, out);
}

// Round 13
// 377.831 us; speedup vs baseline: 2.4709x; 2.1615x over previous
//
#include <hip/hip_runtime.h>
#include <math.h>

#define BB 256
#define TT 512
#define KK 128
#define AIDX(i) ((i) + (((i) >> 5) << 2))

// shared-memory layout (floats) for the fused kernel
#define SM_TT    0          // [128][130] transposed trans = 16640
#define SM_AV    16640      // av[2][144] = 288   (vit)  | ev[2][144] (fwd)
#define SM_TAGS  16928      // tagsf[512]
#define SM_RV    17440      // rv[8]
#define SM_RI    17448      // ri[8]
#define SM_LAST  17456      // last_s
#define SM_WMAX  17460      // wmax[16] (fwd)
#define SM_RS    17476      // rs[8]   (fwd)
#define SM_RSC   17484      // rsc[8]  (fwd)
#define SM_TOTAL 17496      // ~70.0 KB -> 2 blocks/CU

typedef float v2f __attribute__((ext_vector_type(2)));
typedef unsigned short u16v2 __attribute__((ext_vector_type(2)));

template<int CTRL>
__device__ __forceinline__ int dpp_i(int x) {
  return __builtin_amdgcn_update_dpp(x, x, CTRL, 0xF, 0xF, true);
}
template<int CTRL>
__device__ __forceinline__ float dpp_f(float x) {
  return __int_as_float(dpp_i<CTRL>(__float_as_int(x)));
}
__device__ __forceinline__ float swz16_f(float x) {
  return __int_as_float(__builtin_amdgcn_ds_swizzle(__float_as_int(x), 0x401F));
}
__device__ __forceinline__ int pkminu16(int a, int b) {
  u16v2 av = *(u16v2*)&a, bv = *(u16v2*)&b;
  u16v2 r = __builtin_elementwise_min(av, bv);
  return *(int*)&r;
}
// barrier that drains LDS only (not vmcnt) — keeps prefetch loads in flight
#define BARRIER_LGKM() asm volatile("s_waitcnt lgkmcnt(0)\ns_barrier" ::: "memory")

// ============================================================================
// FUSED kernel (R7-verified, 381us e2e): blocks [0,BB): scan-free viterbi
// recursion (streams m_t) then wave 0 runs the equality-match backtrack chase
// in-block (waves 1-7 retire; chase overlaps other blocks' recursions).
// Blocks [BB,2BB): forward log-norm (verbatim 438us-baseline structure).
// ============================================================================
__global__ __launch_bounds__(512, 4) void crf_main(
    const float* __restrict__ logits,     // [B,T,K]
    const int* __restrict__ labels,       // [B,T]
    const int* __restrict__ seq_lens,     // [B]
    const float* __restrict__ trans,      // [K,K]
    float* __restrict__ pred_out,         // [B,T] as float (d_out+1)
    float* __restrict__ negll,            // [B] in ws
    float* __restrict__ mOut)             // [B][T][K] in ws (t>=1 valid)
{
  __shared__ __align__(16) float smem[SM_TOTAL];
  const int tid = threadIdx.x;
  const int cg = tid >> 3, rg = tid & 7;
  const int j0 = cg * 2, i0 = rg * 16;

  if (blockIdx.x < BB) {
    // ================= VITERBI (scan-free) + in-block chase =================
    const int b = blockIdx.x;
    const int L = seq_lens[b];
    float* tT    = smem + SM_TT;                      // [128][130]
    float (*av)[144] = (float(*)[144])(smem + SM_AV);
    float* tagsf = smem + SM_TAGS;
    float* rv    = smem + SM_RV;
    int*   ri    = (int*)(smem + SM_RI);
    int*   last_s = (int*)(smem + SM_LAST);

    // build transposed trans for the chase (coalesced reads, one-time)
    for (int e = tid; e < KK * KK; e += 512) {
      int i = e >> 7, j = e & 127;
      tT[j * 130 + i] = trans[e];
    }

    v2f tv[16];
#pragma unroll
    for (int ii = 0; ii < 16; ++ii)
      tv[ii] = *(const v2f*)&trans[(i0 + ii) * KK + j0];

    if (tid < KK) av[0][AIDX(tid)] = logits[(b * TT) * KK + tid];

    v2f emC[4], emN[4];
#pragma unroll
    for (int s = 0; s < 4; ++s) {
      int t2 = 1 + s; if (t2 > L - 1) t2 = (L > 1) ? (L - 1) : 0;
      emC[s] = *(const v2f*)&logits[(b * TT + t2) * KK + j0];
    }
    __syncthreads();

    for (int tc = 1; tc < L; tc += 4) {
#pragma unroll
      for (int s = 0; s < 4; ++s) {
        int t2 = tc + 4 + s; if (t2 > L - 1) t2 = L - 1;
        emN[s] = *(const v2f*)&logits[(b * TT + t2) * KK + j0];
      }
#pragma unroll
      for (int s = 0; s < 4; ++s) {
        const int t = tc + s;
        if (t >= L) break;
        const float4* avr = (const float4*)(av[(t & 1) ^ 1] + AIDX(i0));
        v2f sv[16];
#pragma unroll
        for (int q = 0; q < 4; ++q) {
          float4 a4 = avr[q];
#pragma unroll
          for (int c = 0; c < 4; ++c) {
            float a = (c == 0) ? a4.x : (c == 1) ? a4.y : (c == 2) ? a4.z : a4.w;
            sv[q * 4 + c] = (v2f){a, a} + tv[q * 4 + c];   // exact IEEE adds
          }
        }
        // in-thread max tree (exact; max is order-insensitive, returns operand bits)
        v2f m;
        {
          v2f m0 = __builtin_elementwise_max(sv[0], sv[1]);
          v2f m1 = __builtin_elementwise_max(sv[2], sv[3]);
          v2f m2 = __builtin_elementwise_max(sv[4], sv[5]);
          v2f m3 = __builtin_elementwise_max(sv[6], sv[7]);
          v2f m4 = __builtin_elementwise_max(sv[8], sv[9]);
          v2f m5 = __builtin_elementwise_max(sv[10], sv[11]);
          v2f m6 = __builtin_elementwise_max(sv[12], sv[13]);
          v2f m7 = __builtin_elementwise_max(sv[14], sv[15]);
          m0 = __builtin_elementwise_max(m0, m1);
          m2 = __builtin_elementwise_max(m2, m3);
          m4 = __builtin_elementwise_max(m4, m5);
          m6 = __builtin_elementwise_max(m6, m7);
          m0 = __builtin_elementwise_max(m0, m2);
          m4 = __builtin_elementwise_max(m4, m6);
          m = __builtin_elementwise_max(m0, m4);
        }
        // cross-row-group max: xor1, xor2, xor4 — all DPP
        {
          v2f o;
          o.x = dpp_f<0xB1>(m.x); o.y = dpp_f<0xB1>(m.y);
          m = __builtin_elementwise_max(m, o);
          o.x = dpp_f<0x4E>(m.x); o.y = dpp_f<0x4E>(m.y);
          m = __builtin_elementwise_max(m, o);
          o.x = dpp_f<0x141>(m.x); o.y = dpp_f<0x141>(m.y);
          m = __builtin_elementwise_max(m, o);
        }
        v2f nav = m + emC[s];
        if (rg == 0) {
          *(v2f*)(av[t & 1] + AIDX(j0)) = nav;
          *(v2f*)&mOut[(b * TT + t) * KK + j0] = m;   // stream m_t
        }
        BARRIER_LGKM();
      }
#pragma unroll
      for (int s = 0; s < 4; ++s) emC[s] = emN[s];
    }

    // final argmax across K → last_s
    const float* avf = av[(L - 1) & 1];
    {
      float v = (tid < KK) ? avf[AIDX(tid)] : -3.4e38f;
      int idx = (tid < KK) ? tid : KK;
#pragma unroll
      for (int mm = 1; mm < 64; mm <<= 1) {
        float ov = __shfl_xor(v, mm);
        int oi = __shfl_xor(idx, mm);
        if (ov > v || (ov == v && oi < idx)) { v = ov; idx = oi; }
      }
      if ((tid & 63) == 0) { rv[tid >> 6] = v; ri[tid >> 6] = idx; }
    }
    __syncthreads();
    if (tid == 0) {
      float bv = rv[0]; int bi = ri[0];
#pragma unroll
      for (int w = 1; w < 8; ++w)
        if (rv[w] > bv || (rv[w] == bv && ri[w] < bi)) { bv = rv[w]; bi = ri[w]; }
      *last_s = bi;
    }
    __syncthreads();
    const int last = *last_s;
    // init all tags to last (chase overwrites 0..L-2)
    for (int t = tid; t < TT; t += 512) tagsf[t] = (float)last;
    // this barrier: (a) tagsf init visible to wave 0, (b) drains every wave's
    // vmcnt (compiler emits vmcnt(0) before s_barrier) so mOut writes are in L2
    __syncthreads();

    if (tid >= 64) return;        // waves 1-7 retire; wave 0 runs the chase
    const int l = tid;

    if (L >= 2) {
      const float* mb = mOut   + (size_t)(b * TT) * KK + 2 * l;
      const float* gb = logits + (size_t)(b * TT) * KK + 2 * l;
      int tag = last;
      v2f mvC = *(const v2f*)&mb[(size_t)(L - 1) * KK];   // m at current step t

      // 8-deep pipeline: stage p holds (logits,m) rows for time t-1-p at loop
      // top. Unconditional clamped loads; clamped rows never consumed unguarded.
      v2f lg0, lg1, lg2, lg3, lg4, lg5, lg6, lg7;
      v2f mv0, mv1, mv2, mv3, mv4, mv5, mv6, mv7;
#define INITLD(P) { int s_ = L - 2 - (P); int sc_ = s_ < 0 ? 0 : s_;           \
      lg##P = *(const v2f*)&gb[(size_t)sc_ * KK];                              \
      mv##P = *(const v2f*)&mb[(size_t)sc_ * KK]; }
      INITLD(0) INITLD(1) INITLD(2) INITLD(3)
      INITLD(4) INITLD(5) INITLD(6) INITLD(7)
#undef INITLD

      int t = L - 1;

#define STEP_BODY(LG, MV, GUARDED)                                             \
      {                                                                        \
        const int tp = t - 1;                                                  \
        v2f aP;                                                                \
        if (GUARDED) aP = (tp >= 1) ? (MV + LG) : LG;                          \
        else         aP = MV + LG;                                             \
        int lanem = tag >> 1;                                                  \
        int txi = __builtin_amdgcn_readlane(__float_as_int(mvC.x), lanem);     \
        int tyi = __builtin_amdgcn_readlane(__float_as_int(mvC.y), lanem);     \
        float target = __int_as_float((tag & 1) ? tyi : txi);                  \
        v2f col = *(const v2f*)&tT[tag * 130 + 2 * l];                         \
        v2f sv = aP + col;                 /* bit-exact phase-1 adds */        \
        bool h0 = (sv.x == target), h1 = (sv.y == target);                     \
        unsigned long long mask = __ballot(h0 || h1);                          \
        int first = __ffsll(mask) - 1;     /* lowest matching lane */          \
        int cand = h0 ? (2 * l) : (2 * l + 1);                                 \
        tag = __builtin_amdgcn_readlane(cand, first);                          \
        if (l == 0) tagsf[tp] = (float)tag;                                    \
        mvC = MV;                                                              \
      }

      // main loop: 8 steps per group, all tp>=1, refill stage p with time t-9
      while (t >= 9) {
#define MAIN_PHASE(P)                                                          \
        STEP_BODY(lg##P, mv##P, false)                                         \
        { int sN = t - 9; int sc_ = sN < 0 ? 0 : sN;                           \
          lg##P = *(const v2f*)&gb[(size_t)sc_ * KK];                          \
          mv##P = *(const v2f*)&mb[(size_t)sc_ * KK]; }                        \
        --t;
        MAIN_PHASE(0) MAIN_PHASE(1) MAIN_PHASE(2) MAIN_PHASE(3)
        MAIN_PHASE(4) MAIN_PHASE(5) MAIN_PHASE(6) MAIN_PHASE(7)
#undef MAIN_PHASE
      }

      // epilogue: <=8 remaining steps, direct loads, tp==0 guard
      while (t >= 1) {
        const int tp = t - 1;
        int sc_ = tp < 1 ? 0 : tp;
        v2f lgE = *(const v2f*)&gb[(size_t)tp * KK];
        v2f mvE = *(const v2f*)&mb[(size_t)sc_ * KK];
        STEP_BODY(lgE, mvE, true)
        --t;
      }
#undef STEP_BODY
    }
    // wave-0 local: lgkmcnt ordering handled by compiler on tagsf reads
#pragma unroll
    for (int k = 0; k < 8; ++k)
      pred_out[b * TT + l * 8 + k] = tagsf[l * 8 + k];

  } else {
    // ================= FORWARD (log-norm) — verbatim 438us baseline =========
    const int b = blockIdx.x - BB;
    const int L = seq_lens[b];
    float (*ev)[144] = (float(*)[144])(smem + SM_AV);
    float* wmax = smem + SM_WMAX;
    float* rs   = smem + SM_RS;
    float* rsc  = smem + SM_RSC;

    v2f tw[16];
#pragma unroll
    for (int ii = 0; ii < 16; ++ii) {
      v2f tr = *(const v2f*)&trans[(i0 + ii) * KK + j0];
      tw[ii].x = __expf(tr.x);
      tw[ii].y = __expf(tr.y);
    }
    if (tid < KK) ev[0][AIDX(tid)] = __expf(logits[(b * TT) * KK + tid]);
    if (tid < 16) wmax[tid] = 1.0f;

    v2f emC[4], emN[4];
#pragma unroll
    for (int s = 0; s < 4; ++s) {
      int t2 = 1 + s; if (t2 > L - 1) t2 = (L > 1) ? (L - 1) : 0;
      emC[s] = *(const v2f*)&logits[(b * TT + t2) * KK + j0];
    }
    __syncthreads();

    float Cln = 0.0f;
    for (int tc = 1; tc < L; tc += 4) {
#pragma unroll
      for (int s = 0; s < 4; ++s) {
        int t2 = tc + 4 + s; if (t2 > L - 1) t2 = L - 1;
        emN[s] = *(const v2f*)&logits[(b * TT + t2) * KK + j0];
      }
      // renorm factor (exact pow2), once per 4-step chunk
      float r;
      {
        float4 w0 = *(const float4*)&wmax[0];
        float4 w1 = *(const float4*)&wmax[4];
        float4 w2 = *(const float4*)&wmax[8];
        float4 w3 = *(const float4*)&wmax[12];
        float U = fmaxf(fmaxf(fmaxf(w0.x, w0.y), fmaxf(w0.z, w0.w)),
                        fmaxf(fmaxf(w1.x, w1.y), fmaxf(w1.z, w1.w)));
        U = fmaxf(U, fmaxf(fmaxf(fmaxf(w2.x, w2.y), fmaxf(w2.z, w2.w)),
                           fmaxf(fmaxf(w3.x, w3.y), fmaxf(w3.z, w3.w))));
        int ex = (__float_as_int(U) >> 23) & 255;
        r = __int_as_float((254 - ex) << 23);
        Cln += (float)(ex - 127) * 0.6931471805599453f;
      }
#pragma unroll
      for (int s = 0; s < 4; ++s) {
        const int t = tc + s;
        if (t >= L) break;
        const float4* evr = (const float4*)(ev[(t & 1) ^ 1] + AIDX(i0));
        v2f S2 = {0.0f, 0.0f};
#pragma unroll
        for (int q = 0; q < 4; ++q) {
          float4 e4 = evr[q];
#pragma unroll
          for (int c = 0; c < 4; ++c) {
            float e = (c == 0) ? e4.x : (c == 1) ? e4.y : (c == 2) ? e4.z : e4.w;
            S2 += (v2f){e, e} * tw[q * 4 + c];   // pk_fma
          }
        }
        {
          v2f o;
          o.x = dpp_f<0xB1>(S2.x); o.y = dpp_f<0xB1>(S2.y); S2 += o;
          o.x = dpp_f<0x4E>(S2.x); o.y = dpp_f<0x4E>(S2.y); S2 += o;
          o.x = dpp_f<0x141>(S2.x); o.y = dpp_f<0x141>(S2.y); S2 += o;
        }
        v2f em2 = emC[s];
        float evn0 = S2.x * __expf(em2.x);
        float evn1 = S2.y * __expf(em2.y);
        if (s == 0) { evn0 *= r; evn1 *= r; }
        if (rg == 0)
          *(v2f*)(ev[t & 1] + AIDX(j0)) = (v2f){evn0, evn1};
        if (s == 3) {
          float wm = fmaxf(evn0, evn1);
          wm = fmaxf(wm, dpp_f<0x140>(wm));   // xor8 (values 8-uniform)
          wm = fmaxf(wm, swz16_f(wm));        // xor16
          if ((tid & 31) == 0) wmax[tid >> 5] = wm;
        }
        BARRIER_LGKM();
      }
#pragma unroll
      for (int s = 0; s < 4; ++s) emC[s] = emN[s];
    }

    const float* evf = ev[(L - 1) & 1];
    {
      float ssum = (tid < KK) ? evf[AIDX(tid)] : 0.0f;
#pragma unroll
      for (int mm = 1; mm < 64; mm <<= 1) ssum += __shfl_xor(ssum, mm);
      if ((tid & 63) == 0) rs[tid >> 6] = ssum;
    }
    float sc = 0.0f;
    for (int tt2 = tid; tt2 < L; tt2 += 512) {
      int lab = labels[b * TT + tt2];
      sc += logits[(b * TT + tt2) * KK + lab];
      if (tt2 >= 1) sc += trans[labels[b * TT + tt2 - 1] * KK + lab];
    }
#pragma unroll
    for (int mm = 1; mm < 64; mm <<= 1) sc += __shfl_xor(sc, mm);
    if ((tid & 63) == 0) rsc[tid >> 6] = sc;
    __syncthreads();
    if (tid == 0) {
      float es = rs[0]; float scf = rsc[0];
#pragma unroll
      for (int w = 1; w < 8; ++w) { es += rs[w]; scf += rsc[w]; }
      negll[b] = (Cln + logf(es)) - scf;
    }
  }
}

// ============================================================================
// FALLBACK: verbatim 438us two-block kernel (bp in ws), used if ws too small.
// ============================================================================
__global__ __launch_bounds__(512, 4) void crf_main_fb(
    const float* __restrict__ logits,
    const int* __restrict__ labels,
    const int* __restrict__ seq_lens,
    const float* __restrict__ trans,
    float* __restrict__ pred_out,
    float* __restrict__ negll,
    unsigned char* __restrict__ bp)
{
  const int tid = threadIdx.x;
  const int cg = tid >> 3, rg = tid & 7;
  const int j0 = cg * 2, i0 = rg * 16;

  if (blockIdx.x < BB) {
    const int b = blockIdx.x;
    const int L = seq_lens[b];
    __shared__ __align__(16) float av[2][144];
    __shared__ unsigned char tags[TT];
    __shared__ float rv[8]; __shared__ int ri[8];
    __shared__ int last_s;

    v2f tv[16];
#pragma unroll
    for (int ii = 0; ii < 16; ++ii)
      tv[ii] = *(const v2f*)&trans[(i0 + ii) * KK + j0];

    if (tid < KK) av[0][AIDX(tid)] = logits[(b * TT) * KK + tid];

    v2f emC[4], emN[4];
#pragma unroll
    for (int s = 0; s < 4; ++s) {
      int t2 = 1 + s; if (t2 > L - 1) t2 = (L > 1) ? (L - 1) : 0;
      emC[s] = *(const v2f*)&logits[(b * TT + t2) * KK + j0];
    }
    __syncthreads();

    unsigned int pw0 = 0, pw1 = 0; int pend_c = -1;

    for (int tc = 1; tc < L; tc += 4) {
#pragma unroll
      for (int s = 0; s < 4; ++s) {
        int t2 = tc + 4 + s; if (t2 > L - 1) t2 = L - 1;
        emN[s] = *(const v2f*)&logits[(b * TT + t2) * KK + j0];
      }
      if (pend_c >= 0 && rg == 1) {
        *(uint2*)(bp + (((b << 7) + pend_c) << 9) + (cg << 3)) =
            make_uint2(pw0, pw1);
      }
      unsigned int w0 = 0, w1 = 0;
#pragma unroll
      for (int s = 0; s < 4; ++s) {
        const int t = tc + s;
        if (t >= L) break;
        const float4* avr = (const float4*)(av[(t & 1) ^ 1] + AIDX(i0));
        v2f sv[16];
#pragma unroll
        for (int q = 0; q < 4; ++q) {
          float4 a4 = avr[q];
#pragma unroll
          for (int c = 0; c < 4; ++c) {
            float a = (c == 0) ? a4.x : (c == 1) ? a4.y : (c == 2) ? a4.z : a4.w;
            sv[q * 4 + c] = (v2f){a, a} + tv[q * 4 + c];
          }
        }
        v2f m;
        {
          v2f m0 = __builtin_elementwise_max(sv[0], sv[1]);
          v2f m1 = __builtin_elementwise_max(sv[2], sv[3]);
          v2f m2 = __builtin_elementwise_max(sv[4], sv[5]);
          v2f m3 = __builtin_elementwise_max(sv[6], sv[7]);
          v2f m4 = __builtin_elementwise_max(sv[8], sv[9]);
          v2f m5 = __builtin_elementwise_max(sv[10], sv[11]);
          v2f m6 = __builtin_elementwise_max(sv[12], sv[13]);
          v2f m7 = __builtin_elementwise_max(sv[14], sv[15]);
          m0 = __builtin_elementwise_max(m0, m1);
          m2 = __builtin_elementwise_max(m2, m3);
          m4 = __builtin_elementwise_max(m4, m5);
          m6 = __builtin_elementwise_max(m6, m7);
          m0 = __builtin_elementwise_max(m0, m2);
          m4 = __builtin_elementwise_max(m4, m6);
          m = __builtin_elementwise_max(m0, m4);
        }
        {
          v2f o;
          o.x = dpp_f<0xB1>(m.x); o.y = dpp_f<0xB1>(m.y);
          m = __builtin_elementwise_max(m, o);
          o.x = dpp_f<0x4E>(m.x); o.y = dpp_f<0x4E>(m.y);
          m = __builtin_elementwise_max(m, o);
          o.x = dpp_f<0x141>(m.x); o.y = dpp_f<0x141>(m.y);
          m = __builtin_elementwise_max(m, o);
        }
        int ai0 = 0xFFFF, ai1 = 0xFFFF;
#pragma unroll
        for (int i = 15; i >= 0; --i) {
          ai0 = (sv[i].x == m.x) ? (i0 + i) : ai0;
          ai1 = (sv[i].y == m.y) ? (i0 + i) : ai1;
        }
        int aip = ai0 | (ai1 << 16);
        aip = pkminu16(aip, dpp_i<0xB1>(aip));
        aip = pkminu16(aip, dpp_i<0x4E>(aip));
        aip = pkminu16(aip, dpp_i<0x141>(aip));

        v2f em2 = emC[s];
        if (rg == 0)
          *(v2f*)(av[t & 1] + AIDX(j0)) = m + em2;
        unsigned int pk = ((unsigned int)aip & 0xFFu) |
                          (((unsigned int)aip >> 8) & 0xFF00u);
        unsigned int sh = pk << ((s & 1) * 16);
        if (s < 2) w0 |= sh; else w1 |= sh;
        BARRIER_LGKM();
      }
      pw0 = w0; pw1 = w1; pend_c = (tc - 1) >> 2;
#pragma unroll
      for (int s = 0; s < 4; ++s) emC[s] = emN[s];
    }
    if (pend_c >= 0 && rg == 1) {
      *(uint2*)(bp + (((b << 7) + pend_c) << 9) + (cg << 3)) =
          make_uint2(pw0, pw1);
    }

    const float* avf = av[(L - 1) & 1];
    {
      float v = (tid < KK) ? avf[AIDX(tid)] : -3.4e38f;
      int idx = (tid < KK) ? tid : KK;
#pragma unroll
      for (int mm = 1; mm < 64; mm <<= 1) {
        float ov = __shfl_xor(v, mm);
        int oi = __shfl_xor(idx, mm);
        if (ov > v || (ov == v && oi < idx)) { v = ov; idx = oi; }
      }
      if ((tid & 63) == 0) { rv[tid >> 6] = v; ri[tid >> 6] = idx; }
    }
    __syncthreads();
    if (tid == 0) {
      float bv = rv[0]; int bi = ri[0];
#pragma unroll
      for (int w = 1; w < 8; ++w)
        if (rv[w] > bv || (rv[w] == bv && ri[w] < bi)) { bv = rv[w]; bi = ri[w]; }
      last_s = bi;
    }
    __syncthreads();
    const int last = last_s;
    if (tid >= L - 1 && tid < TT) tags[tid] = (unsigned char)last;
    __syncthreads();

    if (tid < 64 && L >= 2) {
      const uint2* bpv = (const uint2*)bp;
      int tag = last;
      int cTop = (L - 2) >> 2;
      uint2 q = bpv[(((b << 7) + cTop) << 6) + tid];
      for (int c = cTop; c >= 0; --c) {
        uint2 qn;
        if (c > 0) qn = bpv[(((b << 7) + (c - 1)) << 6) + tid];
        int sHi = (L - 2) - 4 * c; if (sHi > 3) sHi = 3;
#pragma unroll
        for (int s = 3; s >= 0; --s) {
          if (s <= sHi) {
            int word = (s < 2) ? (int)q.x : (int)q.y;
            unsigned int w = (unsigned int)__shfl(word, tag >> 1);
            tag = (int)((w >> ((((s & 1) << 1) | (tag & 1)) << 3)) & 255u);
            if (tid == 0) tags[4 * c + s] = (unsigned char)tag;
          }
        }
        q = qn;
      }
    }
    __syncthreads();
    pred_out[b * TT + tid] = (float)tags[tid];

  } else {
    const int b = blockIdx.x - BB;
    const int L = seq_lens[b];
    __shared__ __align__(16) float ev[2][144];
    __shared__ __align__(16) float wmax[16];
    __shared__ float rs[8]; __shared__ float rsc[8];

    v2f tw[16];
#pragma unroll
    for (int ii = 0; ii < 16; ++ii) {
      v2f tr = *(const v2f*)&trans[(i0 + ii) * KK + j0];
      tw[ii].x = __expf(tr.x);
      tw[ii].y = __expf(tr.y);
    }
    if (tid < KK) ev[0][AIDX(tid)] = __expf(logits[(b * TT) * KK + tid]);
    if (tid < 16) wmax[tid] = 1.0f;

    v2f emC[4], emN[4];
#pragma unroll
    for (int s = 0; s < 4; ++s) {
      int t2 = 1 + s; if (t2 > L - 1) t2 = (L > 1) ? (L - 1) : 0;
      emC[s] = *(const v2f*)&logits[(b * TT + t2) * KK + j0];
    }
    __syncthreads();

    float Cln = 0.0f;
    for (int tc = 1; tc < L; tc += 4) {
#pragma unroll
      for (int s = 0; s < 4; ++s) {
        int t2 = tc + 4 + s; if (t2 > L - 1) t2 = L - 1;
        emN[s] = *(const v2f*)&logits[(b * TT + t2) * KK + j0];
      }
      float r;
      {
        float4 w0 = *(const float4*)&wmax[0];
        float4 w1 = *(const float4*)&wmax[4];
        float4 w2 = *(const float4*)&wmax[8];
        float4 w3 = *(const float4*)&wmax[12];
        float U = fmaxf(fmaxf(fmaxf(w0.x, w0.y), fmaxf(w0.z, w0.w)),
                        fmaxf(fmaxf(w1.x, w1.y), fmaxf(w1.z, w1.w)));
        U = fmaxf(U, fmaxf(fmaxf(fmaxf(w2.x, w2.y), fmaxf(w2.z, w2.w)),
                           fmaxf(fmaxf(w3.x, w3.y), fmaxf(w3.z, w3.w))));
        int ex = (__float_as_int(U) >> 23) & 255;
        r = __int_as_float((254 - ex) << 23);
        Cln += (float)(ex - 127) * 0.6931471805599453f;
      }
#pragma unroll
      for (int s = 0; s < 4; ++s) {
        const int t = tc + s;
        if (t >= L) break;
        const float4* evr = (const float4*)(ev[(t & 1) ^ 1] + AIDX(i0));
        v2f S2 = {0.0f, 0.0f};
#pragma unroll
        for (int q = 0; q < 4; ++q) {
          float4 e4 = evr[q];
#pragma unroll
          for (int c = 0; c < 4; ++c) {
            float e = (c == 0) ? e4.x : (c == 1) ? e4.y : (c == 2) ? e4.z : e4.w;
            S2 += (v2f){e, e} * tw[q * 4 + c];
          }
        }
        {
          v2f o;
          o.x = dpp_f<0xB1>(S2.x); o.y = dpp_f<0xB1>(S2.y); S2 += o;
          o.x = dpp_f<0x4E>(S2.x); o.y = dpp_f<0x4E>(S2.y); S2 += o;
          o.x = dpp_f<0x141>(S2.x); o.y = dpp_f<0x141>(S2.y); S2 += o;
        }
        v2f em2 = emC[s];
        float evn0 = S2.x * __expf(em2.x);
        float evn1 = S2.y * __expf(em2.y);
        if (s == 0) { evn0 *= r; evn1 *= r; }
        if (rg == 0)
          *(v2f*)(ev[t & 1] + AIDX(j0)) = (v2f){evn0, evn1};
        if (s == 3) {
          float wm = fmaxf(evn0, evn1);
          wm = fmaxf(wm, dpp_f<0x140>(wm));
          wm = fmaxf(wm, swz16_f(wm));
          if ((tid & 31) == 0) wmax[tid >> 5] = wm;
        }
        BARRIER_LGKM();
      }
#pragma unroll
      for (int s = 0; s < 4; ++s) emC[s] = emN[s];
    }

    const float* evf = ev[(L - 1) & 1];
    {
      float ssum = (tid < KK) ? evf[AIDX(tid)] : 0.0f;
#pragma unroll
      for (int mm = 1; mm < 64; mm <<= 1) ssum += __shfl_xor(ssum, mm);
      if ((tid & 63) == 0) rs[tid >> 6] = ssum;
    }
    float sc = 0.0f;
    for (int tt2 = tid; tt2 < L; tt2 += 512) {
      int lab = labels[b * TT + tt2];
      sc += logits[(b * TT + tt2) * KK + lab];
      if (tt2 >= 1) sc += trans[labels[b * TT + tt2 - 1] * KK + lab];
    }
#pragma unroll
    for (int mm = 1; mm < 64; mm <<= 1) sc += __shfl_xor(sc, mm);
    if ((tid & 63) == 0) rsc[tid >> 6] = sc;
    __syncthreads();
    if (tid == 0) {
      float es = rs[0]; float scf = rsc[0];
#pragma unroll
      for (int w = 1; w < 8; ++w) { es += rs[w]; scf += rsc[w]; }
      negll[b] = (Cln + logf(es)) - scf;
    }
  }
}

__global__ void crf_loss_reduce(const float* __restrict__ negll, float* __restrict__ out) {
  int tid = threadIdx.x;
  float v = negll[tid];
#pragma unroll
  for (int m = 1; m < 64; m <<= 1) v += __shfl_xor(v, m);
  __shared__ float p[4];
  if ((tid & 63) == 0) p[tid >> 6] = v;
  __syncthreads();
  if (tid == 0) out[0] = p[0] + p[1] + p[2] + p[3];
}

extern "C" void kernel_launch(void* const* d_in, const int* in_sizes, int n_in,
                              void* d_out, int out_size, void* d_ws, size_t ws_size,
                              hipStream_t stream) {
  const float* logits   = (const float*)d_in[0];
  const int*   labels   = (const int*)d_in[1];
  const int*   seq_lens = (const int*)d_in[2];
  const float* trans    = (const float*)d_in[3];
  float* out = (float*)d_out;

  float* negll = (float*)d_ws;                          // [0, 1KB): 256 floats
  const size_t M_OFF = 4096;
  const size_t NEED = M_OFF + (size_t)BB * TT * KK * 4;   // ~67.1 MB

  if (ws_size >= NEED) {
    float* mOut = (float*)((char*)d_ws + M_OFF);        // [4KB, 4KB+67.1MB)
    crf_main<<<2 * BB, 512, 0, stream>>>(logits, labels, seq_lens, trans,
                                         out + 1, negll, mOut);
  } else {
    unsigned char* bp = (unsigned char*)d_ws + 1024;    // 16.8 MB
    crf_main_fb<<<2 * BB, 512, 0, stream>>>(logits, labels, seq_lens, trans,
                                            out + 1, negll, bp);
  }
  crf_loss_reduce<<<1, 256, 0, stream>>>(negll, out);
}